// Round 11
// baseline (216.810 us; speedup 1.0000x reference)
//
#include <hip/hip_runtime.h>

#define B_    1024
#define TI_   2
#define TE_   3
#define AB_   (TI_ * TE_)
#define BIN_  16
#define BOUT_ 32

typedef float f4 __attribute__((ext_vector_type(4)));
typedef float f4u __attribute__((ext_vector_type(4), aligned(4)));

// out[slice, o, l, k] = sum_i X[slice, i, l] * W[ab, i, o, k]
//
// R11 = R9 + NON-TEMPORAL stores (single-variable A/B vs R9's 152.7us).
// Theory: the 150us plateau across three structurally different kernels is
// L2 write-allocate (RFO) on partial-line stores: every 128B output line is
// fetched from HBM before being written -> 888MB of traffic instead of
// 444MB. nt = no-allocate streaming hint; the block's spatially-dense 16B
// pieces write-combine in the MC. If RFO is real: ~90-110us. If neutral:
// theory dead, attack occupancy next. If >180: nt broke write-combining.
//
// Structure (R9, unchanged): thread = (slice, o, k-quad); X row-set lives
// wave-spread in <=5 VGPRs, fetched per (i,l) with compile-time v_readlane;
// W hoisted (16 x f4); acc[NSH] f4 stored directly (4B-aligned 16B stores);
// tail quads overlap (k0 = min(4q, NSH-4)), duplicate threads store
// identical bytes (benign).
template<int NSH, int QTP, int SPB, int BLOCK>
__global__ __launch_bounds__(BLOCK)
void conv_dst(const float* __restrict__ X, const float* __restrict__ W,
              float* __restrict__ OUT) {
    constexpr int TS   = 32 * QTP;        // threads per slice (wave multiple)
    constexpr int SZ   = BIN_ * NSH;      // X floats per slice
    constexpr int XR   = (SZ + 63) / 64;  // wave-spread X VGPRs
    constexpr int NOUT = BOUT_ * NSH * NSH;
    static_assert(SPB * TS == BLOCK, "geometry");
    static_assert(TS % 64 == 0, "wave-aligned slices");

    const int tid  = threadIdx.x;
    const int lane = tid & 63;
    const int sl   = tid / TS;            // wave-uniform
    const int wid  = tid - sl * TS;
    const int o    = wid / QTP;
    const int q    = wid - o * QTP;
    const int k0   = (4 * q > NSH - 4) ? (NSH - 4) : (4 * q);
    const int slice = blockIdx.x * SPB + sl;
    const int ab    = slice % AB_;

    // ---- X row-set into wave-spread VGPRs (coalesced; clamped tail slots
    //      are never readlane'd) ----
    const float* Xs = X + (size_t)slice * SZ;
    float xr[XR];
#pragma unroll
    for (int c = 0; c < XR; ++c) {
        int idx = c * 64 + lane;
        if (idx > SZ - 1) idx = SZ - 1;
        xr[c] = Xs[idx];
    }

    // ---- hoist W (this thread's k-quad, all i); 16B loads, 4B-aligned ok ----
    const float* Wp = W + (size_t)ab * (BIN_ * BOUT_ * NSH) + o * NSH + k0;
    f4 wreg[BIN_];
#pragma unroll
    for (int i = 0; i < BIN_; ++i)
        __builtin_memcpy(&wreg[i], Wp + (size_t)i * (BOUT_ * NSH), 16);

    f4 acc[NSH];
#pragma unroll
    for (int l = 0; l < NSH; ++l) acc[l] = (f4){0.f, 0.f, 0.f, 0.f};

#pragma unroll
    for (int i = 0; i < BIN_; ++i) {
#pragma unroll
        for (int l = 0; l < NSH; ++l) {
            const int idx = i * NSH + l;                    // compile-time
            const float xv = __int_as_float(
                __builtin_amdgcn_readlane(__float_as_int(xr[idx >> 6]),
                                          idx & 63));
            const f4 xb = {xv, xv, xv, xv};
            acc[l] = __builtin_elementwise_fma(xb, wreg[i], acc[l]);
        }
    }

    // ---- direct 16B NON-TEMPORAL stores (no L2 write-allocate) ----
    float* Op = OUT + (size_t)slice * NOUT + o * (NSH * NSH) + k0;
#pragma unroll
    for (int l = 0; l < NSH; ++l)
        __builtin_nontemporal_store(acc[l], (f4u*)(Op + l * NSH));
}

// l=0: direct coalesced stores, 64 n per block.
__global__ __launch_bounds__(256)
void conv_l0_kernel(const float* __restrict__ X, const float* __restrict__ W,
                    const float* __restrict__ bias, float* __restrict__ OUT) {
    const int o  = threadIdx.x & 31;
    const int ns = threadIdx.x >> 5;   // 0..7
    const int b  = blockIdx.x;
    const int n0 = (b / AB_) * 64;
    const int ab = b % AB_;
    float wv[BIN_];
#pragma unroll
    for (int i = 0; i < BIN_; ++i) wv[i] = W[(ab * BIN_ + i) * BOUT_ + o];
    const float bv = bias[ab * BOUT_ + o];
#pragma unroll
    for (int s = 0; s < 8; ++s) {
        const int n = n0 + ns + s * 8;
        const float* Xp = X + ((size_t)n * AB_ + ab) * BIN_;
        float acc = bv;
#pragma unroll
        for (int i = 0; i < BIN_; ++i) acc = fmaf(Xp[i], wv[i], acc);
        __builtin_nontemporal_store(acc, &OUT[((size_t)n * AB_ + ab) * BOUT_ + o]);
    }
}

extern "C" void kernel_launch(void* const* d_in, const int* in_sizes, int n_in,
                              void* d_out, int out_size, void* d_ws, size_t ws_size,
                              hipStream_t stream) {
    const float* x0 = (const float*)d_in[0];
    const float* w0 = (const float*)d_in[1];
    const float* x2 = (const float*)d_in[2];
    const float* w2 = (const float*)d_in[3];
    const float* x4 = (const float*)d_in[4];
    const float* w4 = (const float*)d_in[5];
    const float* x6 = (const float*)d_in[6];
    const float* w6 = (const float*)d_in[7];
    const float* x8 = (const float*)d_in[8];
    const float* w8 = (const float*)d_in[9];
    const float* bias = (const float*)d_in[10];
    float* out = (float*)d_out;

    const size_t per = (size_t)B_ * AB_ * BOUT_;
    size_t off0 = 0;
    size_t off2 = off0 + per * 1;
    size_t off4 = off2 + per * 25;
    size_t off6 = off4 + per * 81;
    size_t off8 = off6 + per * 169;

    const int S = B_ * AB_;  // 6144 slices

    //        NSH QTP SPB BLOCK          grid      (k0 pattern)
    conv_dst<17, 6, 2, 384><<<S / 2, 384, 0, stream>>>(x8, w8, out + off8); // 0,4,8,12,13,13
    conv_dst<13, 4, 2, 256><<<S / 2, 256, 0, stream>>>(x6, w6, out + off6); // 0,4,8,9
    conv_dst< 9, 4, 2, 256><<<S / 2, 256, 0, stream>>>(x4, w4, out + off4); // 0,4,5,5
    conv_dst< 5, 2, 8, 512><<<S / 8, 512, 0, stream>>>(x2, w2, out + off2); // 0,1
    conv_l0_kernel<<<(B_ / 64) * AB_, 256, 0, stream>>>(x0, w0, bias, out + off0);
}

// Round 12
// 169.581 us; speedup vs baseline: 1.2785x; 1.2785x over previous
//
#include <hip/hip_runtime.h>

#define B_    1024
#define TI_   2
#define TE_   3
#define AB_   (TI_ * TE_)
#define BIN_  16
#define BOUT_ 32

typedef float f4 __attribute__((ext_vector_type(4)));

// out[slice, o, l, k] = sum_i X[slice, i, l] * W[ab, i, o, k]
//
// R12: persistent blocks. R7/R8/R9 plateau at ~150us with W re-fetched per
// slice (l8: 302MB of strided L2 reads + 16-load latency bubble heading
// every wave). Grid chosen so GRID*SPB % 6 == 0 -> each thread's ab (and
// thus its W column) is INVARIANT across grid-stride iterations: W hoisted
// once per kernel. X for the next slice is prefetched into xrn during the
// current FMA loop (software pipeline). Stores: R9's direct 16B (L2 merges
// partial lines -- proven by ideal WRITE_SIZE; nt bypass hurt, R11).
template<int NSH, int QTP, int SPB, int BLOCK, int GRID, int ITERS>
__device__ __forceinline__ void conv_body(const float* __restrict__ X,
                                          const float* __restrict__ W,
                                          float* __restrict__ OUT, int b) {
    constexpr int TS   = 32 * QTP;        // threads per slice (wave multiple)
    constexpr int SZ   = BIN_ * NSH;      // X floats per slice
    constexpr int XR   = (SZ + 63) / 64;  // wave-spread X VGPRs
    constexpr int NOUT = BOUT_ * NSH * NSH;
    static_assert(SPB * TS == BLOCK, "no idle threads");
    static_assert(TS % 64 == 0, "wave-aligned slices (readlane uniformity)");
    static_assert((GRID * SPB) % AB_ == 0, "ab invariant across iterations");
    static_assert(GRID * SPB * ITERS == B_ * AB_, "covers all slices");

    const int tid  = threadIdx.x;
    const int lane = tid & 63;
    const int sl   = tid / TS;            // wave-uniform
    const int wid  = tid - sl * TS;
    const int o    = wid / QTP;
    const int q    = wid - o * QTP;
    const int k0   = (4 * q > NSH - 4) ? (NSH - 4) : (4 * q);

    int slice = b * SPB + sl;
    const int ab = slice % AB_;           // constant for all iterations

    // ---- hoist W once per kernel (this thread's k-quad, all i) ----
    const float* Wp = W + (size_t)ab * (BIN_ * BOUT_ * NSH) + o * NSH + k0;
    f4 wreg[BIN_];
#pragma unroll
    for (int i = 0; i < BIN_; ++i)
        __builtin_memcpy(&wreg[i], Wp + (size_t)i * (BOUT_ * NSH), 16);

    // ---- first slice's X row-set (wave-spread, coalesced) ----
    float xr[XR];
    {
        const float* Xs = X + (size_t)slice * SZ;
#pragma unroll
        for (int c = 0; c < XR; ++c) {
            int idx = c * 64 + lane;
            if (idx > SZ - 1) idx = SZ - 1;
            xr[c] = Xs[idx];
        }
    }

    for (int it = 0; it < ITERS; ++it) {
        // ---- prefetch next slice's X during this slice's FMA ----
        float xrn[XR];
        if (it + 1 < ITERS) {
            const float* Xs = X + (size_t)(slice + GRID * SPB) * SZ;
#pragma unroll
            for (int c = 0; c < XR; ++c) {
                int idx = c * 64 + lane;
                if (idx > SZ - 1) idx = SZ - 1;
                xrn[c] = Xs[idx];
            }
        }

        f4 acc[NSH];
#pragma unroll
        for (int l = 0; l < NSH; ++l) acc[l] = (f4){0.f, 0.f, 0.f, 0.f};

#pragma unroll
        for (int i = 0; i < BIN_; ++i) {
#pragma unroll
            for (int l = 0; l < NSH; ++l) {
                const int idx = i * NSH + l;                    // compile-time
                const float xv = __int_as_float(
                    __builtin_amdgcn_readlane(__float_as_int(xr[idx >> 6]),
                                              idx & 63));
                const f4 xb = {xv, xv, xv, xv};
                acc[l] = __builtin_elementwise_fma(xb, wreg[i], acc[l]);
            }
        }

        // ---- direct 16B stores (dup quads store identical bytes; benign) ----
        float* Op = OUT + (size_t)slice * NOUT + o * (NSH * NSH) + k0;
#pragma unroll
        for (int l = 0; l < NSH; ++l)
            __builtin_memcpy(Op + l * NSH, &acc[l], 16);

        slice += GRID * SPB;
#pragma unroll
        for (int c = 0; c < XR; ++c) xr[c] = xrn[c];
    }
}

// l=0 persistent: 192 blocks x 4 iters x 256 thr; ab per-thread invariant
// (elem stride/iter = 49152 -> slice stride 1536 % 6 == 0) -> W hoisted.
__device__ __forceinline__ void conv_l0(const float* __restrict__ X,
                                        const float* __restrict__ W,
                                        const float* __restrict__ bias,
                                        float* __restrict__ OUT, int b) {
    const int elem0  = b * 256 + threadIdx.x;
    const int slice0 = elem0 >> 5;
    const int o      = elem0 & 31;
    const int ab     = slice0 % AB_;
    float wv[BIN_];
#pragma unroll
    for (int i = 0; i < BIN_; ++i) wv[i] = W[(ab * BIN_ + i) * BOUT_ + o];
    const float bv = bias[ab * BOUT_ + o];
#pragma unroll
    for (int it = 0; it < 4; ++it) {
        const int slice = slice0 + it * 1536;
        const float* Xp = X + (size_t)slice * BIN_;
        float acc = bv;
#pragma unroll
        for (int i = 0; i < BIN_; ++i) acc = fmaf(Xp[i], wv[i], acc);
        OUT[(size_t)slice * BOUT_ + o] = acc;
    }
}

template<int NSH, int QTP, int SPB, int BLOCK, int GRID, int ITERS>
__global__ __launch_bounds__(BLOCK)
void conv_pers(const float* __restrict__ X, const float* __restrict__ W,
               float* __restrict__ OUT) {
    conv_body<NSH, QTP, SPB, BLOCK, GRID, ITERS>(X, W, OUT, blockIdx.x);
}

// small degrees fused (inline branches; VGPR spread modest, all <=~110)
__global__ __launch_bounds__(256)
void conv_small(const float* __restrict__ x0, const float* __restrict__ x2,
                const float* __restrict__ x4,
                const float* __restrict__ w0, const float* __restrict__ w2,
                const float* __restrict__ w4,
                const float* __restrict__ bias, float* __restrict__ out,
                size_t off0, size_t off2, size_t off4) {
    int b = blockIdx.x;
    if (b < 768) { conv_body<9, 4, 2, 256, 768, 4>(x4, w4, out + off4, b); return; }
    b -= 768;
    if (b < 192) { conv_body<5, 2, 4, 256, 192, 8>(x2, w2, out + off2, b); return; }
    b -= 192;
    conv_l0(x0, w0, bias, out + off0, b);   // 192 blocks
}

extern "C" void kernel_launch(void* const* d_in, const int* in_sizes, int n_in,
                              void* d_out, int out_size, void* d_ws, size_t ws_size,
                              hipStream_t stream) {
    const float* x0 = (const float*)d_in[0];
    const float* w0 = (const float*)d_in[1];
    const float* x2 = (const float*)d_in[2];
    const float* w2 = (const float*)d_in[3];
    const float* x4 = (const float*)d_in[4];
    const float* w4 = (const float*)d_in[5];
    const float* x6 = (const float*)d_in[6];
    const float* w6 = (const float*)d_in[7];
    const float* x8 = (const float*)d_in[8];
    const float* w8 = (const float*)d_in[9];
    const float* bias = (const float*)d_in[10];
    float* out = (float*)d_out;

    const size_t per = (size_t)B_ * AB_ * BOUT_;
    size_t off0 = 0;
    size_t off2 = off0 + per * 1;
    size_t off4 = off2 + per * 25;
    size_t off6 = off4 + per * 81;
    size_t off8 = off6 + per * 169;

    //         NSH QTP SPB BLOCK GRID ITERS
    conv_pers<17, 6, 2, 384, 768, 4><<<768, 384, 0, stream>>>(x8, w8, out + off8);
    conv_pers<13, 4, 2, 256, 768, 4><<<768, 256, 0, stream>>>(x6, w6, out + off6);
    conv_small<<<1152, 256, 0, stream>>>(x0, x2, x4, w0, w2, w4, bias, out,
                                         off0, off2, off4);
}

// Round 13
// 164.217 us; speedup vs baseline: 1.3203x; 1.0327x over previous
//
#include <hip/hip_runtime.h>

#define B_    1024
#define TI_   2
#define TE_   3
#define AB_   (TI_ * TE_)
#define BIN_  16
#define BOUT_ 32

typedef float f4 __attribute__((ext_vector_type(4)));

// out[slice, o, l, k] = sum_i X[slice, i, l] * W[ab, i, o, k]
//
// R13 = R9 with ONE change: W is a depth-4 rolling ring (16 VGPR) instead of
// a full 16xf4 hoist (64 VGPR), and __launch_bounds__(BLOCK,4) pins the
// allocator to <=128 VGPR -> 4 waves/SIMD (2x R9).
//
// Model being tested: wave-lifetime store-duty-cycle. Stores issue only in
// the terminal ~8% of a wave's life; at 2 waves/SIMD the expected number of
// concurrently-storing waves per CU is <1 -> the write stream starves at
// ~3 TB/s (the 150us plateau shared by R7/R8/R9 regardless of structure).
// Doubling resident waves doubles store concurrency.
//
// Everything else is R9, proven: thread = (slice, o, k-quad); X row-set
// wave-spread in <=5 VGPRs + compile-time v_readlane; tail quads overlap
// (k0 = min(4q, NSH-4), duplicates store identical bytes -- benign; L2
// merges partial lines, WRITE_SIZE stays ideal, nt bypass hurt in R11).
template<int NSH, int QTP, int SPB, int BLOCK>
__global__ __launch_bounds__(BLOCK, 4)
void conv_roll(const float* __restrict__ X, const float* __restrict__ W,
               float* __restrict__ OUT) {
    constexpr int TS   = 32 * QTP;        // threads per slice (wave multiple)
    constexpr int SZ   = BIN_ * NSH;      // X floats per slice
    constexpr int XR   = (SZ + 63) / 64;  // wave-spread X VGPRs
    constexpr int NOUT = BOUT_ * NSH * NSH;
    static_assert(SPB * TS == BLOCK, "geometry");
    static_assert(TS % 64 == 0, "wave-aligned slices");

    const int tid  = threadIdx.x;
    const int lane = tid & 63;
    const int sl   = tid / TS;            // wave-uniform
    const int wid  = tid - sl * TS;
    const int o    = wid / QTP;
    const int q    = wid - o * QTP;
    const int k0   = (4 * q > NSH - 4) ? (NSH - 4) : (4 * q);
    const int slice = blockIdx.x * SPB + sl;
    const int ab    = slice % AB_;

    // ---- X row-set into wave-spread VGPRs (coalesced; clamped tail slots
    //      are never readlane'd) ----
    const float* Xs = X + (size_t)slice * SZ;
    float xr[XR];
#pragma unroll
    for (int c = 0; c < XR; ++c) {
        int idx = c * 64 + lane;
        if (idx > SZ - 1) idx = SZ - 1;
        xr[c] = Xs[idx];
    }

    const float* Wp = W + (size_t)ab * (BIN_ * BOUT_ * NSH) + o * NSH + k0;

    // ---- depth-4 rolling W ring (16 VGPR), statically indexed ----
    f4 wring[4];
#pragma unroll
    for (int i = 0; i < 4; ++i)
        __builtin_memcpy(&wring[i], Wp + (size_t)i * (BOUT_ * NSH), 16);

    f4 acc[NSH];
#pragma unroll
    for (int l = 0; l < NSH; ++l) acc[l] = (f4){0.f, 0.f, 0.f, 0.f};

#pragma unroll
    for (int i = 0; i < BIN_; ++i) {
        const f4 wv = wring[i & 3];
        if (i + 4 < BIN_)
            __builtin_memcpy(&wring[i & 3], Wp + (size_t)(i + 4) * (BOUT_ * NSH), 16);
#pragma unroll
        for (int l = 0; l < NSH; ++l) {
            const int idx = i * NSH + l;                    // compile-time
            const float xv = __int_as_float(
                __builtin_amdgcn_readlane(__float_as_int(xr[idx >> 6]),
                                          idx & 63));
            const f4 xb = {xv, xv, xv, xv};
            acc[l] = __builtin_elementwise_fma(xb, wv, acc[l]);
        }
    }

    // ---- direct 16B stores (dup quads store identical bytes; benign) ----
    float* Op = OUT + (size_t)slice * NOUT + o * (NSH * NSH) + k0;
#pragma unroll
    for (int l = 0; l < NSH; ++l)
        __builtin_memcpy(Op + l * NSH, &acc[l], 16);
}

// l=0: direct coalesced stores, 64 n per block.
__global__ __launch_bounds__(256)
void conv_l0_kernel(const float* __restrict__ X, const float* __restrict__ W,
                    const float* __restrict__ bias, float* __restrict__ OUT) {
    const int o  = threadIdx.x & 31;
    const int ns = threadIdx.x >> 5;   // 0..7
    const int b  = blockIdx.x;
    const int n0 = (b / AB_) * 64;
    const int ab = b % AB_;
    float wv[BIN_];
#pragma unroll
    for (int i = 0; i < BIN_; ++i) wv[i] = W[(ab * BIN_ + i) * BOUT_ + o];
    const float bv = bias[ab * BOUT_ + o];
#pragma unroll
    for (int s = 0; s < 8; ++s) {
        const int n = n0 + ns + s * 8;
        const float* Xp = X + ((size_t)n * AB_ + ab) * BIN_;
        float acc = bv;
#pragma unroll
        for (int i = 0; i < BIN_; ++i) acc = fmaf(Xp[i], wv[i], acc);
        OUT[((size_t)n * AB_ + ab) * BOUT_ + o] = acc;
    }
}

extern "C" void kernel_launch(void* const* d_in, const int* in_sizes, int n_in,
                              void* d_out, int out_size, void* d_ws, size_t ws_size,
                              hipStream_t stream) {
    const float* x0 = (const float*)d_in[0];
    const float* w0 = (const float*)d_in[1];
    const float* x2 = (const float*)d_in[2];
    const float* w2 = (const float*)d_in[3];
    const float* x4 = (const float*)d_in[4];
    const float* w4 = (const float*)d_in[5];
    const float* x6 = (const float*)d_in[6];
    const float* w6 = (const float*)d_in[7];
    const float* x8 = (const float*)d_in[8];
    const float* w8 = (const float*)d_in[9];
    const float* bias = (const float*)d_in[10];
    float* out = (float*)d_out;

    const size_t per = (size_t)B_ * AB_ * BOUT_;
    size_t off0 = 0;
    size_t off2 = off0 + per * 1;
    size_t off4 = off2 + per * 25;
    size_t off6 = off4 + per * 81;
    size_t off8 = off6 + per * 169;

    const int S = B_ * AB_;  // 6144 slices

    //         NSH QTP SPB BLOCK          grid      (geometry identical to R9)
    conv_roll<17, 6, 2, 384><<<S / 2, 384, 0, stream>>>(x8, w8, out + off8);
    conv_roll<13, 4, 2, 256><<<S / 2, 256, 0, stream>>>(x6, w6, out + off6);
    conv_roll< 9, 4, 2, 256><<<S / 2, 256, 0, stream>>>(x4, w4, out + off4);
    conv_roll< 5, 2, 8, 512><<<S / 8, 512, 0, stream>>>(x2, w2, out + off2);
    conv_l0_kernel<<<(B_ / 64) * AB_, 256, 0, stream>>>(x0, w0, bias, out + off0);
}